// Round 6
// baseline (216.411 us; speedup 1.0000x reference)
//
#include <hip/hip_runtime.h>
#include <float.h>

// B=32, C=256, HW=1024 (64 s-tiles of 16), K=1024, L=64
// d_out = [ out: 8388608 f32 ][ nearest: 2097152 f32 ]
//
// ws layout (float units):
//   wT   [256*64] @ 0      : wT[c*64+l] = W_in[l*256+c]           (fp32)
//   cbn  [1024]   @ 16384  : ||cb_k||^2                           (fp32)
//   cbh  [1024*64] ushort @ float-ofs 17408  (bf16 hi of cb)
//   cbl  [1024*64] ushort  (bf16 lo)
//   wouth[256*64]  ushort  (bf16 hi of W_out)
//   woutl[256*64]  ushort  (bf16 lo)
//
// Kernel split rationale (r3-r5 post-mortems): on gfx950 the allocator gives
// MFMA kernels only ~half the unified RF as arch VGPRs (other half = acc side);
// fused phase1+phase2 exceeded the arch half at every __launch_bounds__ cap
// -> 65-180MB scratch traffic. Splitting z-projection (no MFMA, register-light)
// from the MFMA distance/projection kernel keeps each side within budget.
// z scratch lives in the `nearest` output region: block (b,s0) writes z exactly
// where its own nearest-slice goes later; vq_kernel reads only its own slice
// (stream-ordered after zproj) and overwrites it at the gather step.

typedef __attribute__((ext_vector_type(8))) short short8v;
typedef __attribute__((ext_vector_type(4))) float f32x4;

#define MFMA16(A, B, C) __builtin_amdgcn_mfma_f32_16x16x32_bf16((A), (B), (C), 0, 0, 0)

__device__ __forceinline__ unsigned short f2bf(float f) {
    unsigned int u = __float_as_uint(f);
    u += 0x7FFFu + ((u >> 16) & 1u);
    return (unsigned short)(u >> 16);
}
__device__ __forceinline__ float bf2f(unsigned short h) {
    return __uint_as_float(((unsigned int)h) << 16);
}

__global__ void prep_kernel(const float* __restrict__ Win,
                            const float* __restrict__ Wout,
                            const float* __restrict__ cb,
                            float* __restrict__ ws) {
    __shared__ float tile[64][65];
    unsigned short* cbh   = (unsigned short*)(ws + 17408);
    unsigned short* cbl   = cbh + 65536;
    unsigned short* wouth = cbl + 65536;
    unsigned short* woutl = wouth + 16384;
    float* cbn = ws + 16384;
    float* wT  = ws;
    const int blk = blockIdx.x, t = threadIdx.x;

    if (blk < 256) {
        // codebook bf16 split + ||cb||^2 (one wave per code row: 64 lanes = 64 dims)
        int gid = blk * 256 + t;
        float v = cb[gid];
        unsigned short h = f2bf(v);
        cbh[gid] = h;
        cbl[gid] = f2bf(v - bf2f(h));
        float sq = v * v;
        #pragma unroll
        for (int m = 1; m < 64; m <<= 1) sq += __shfl_xor(sq, m);
        if ((t & 63) == 0) cbn[gid >> 6] = sq;
    } else if (blk < 320) {
        int gid = (blk - 256) * 256 + t;
        float v = Wout[gid];
        unsigned short h = f2bf(v);
        wouth[gid] = h;
        woutl[gid] = f2bf(v - bf2f(h));
    } else {
        // W_in transpose via LDS tile (coalesced both ways)
        int c0 = (blk - 320) * 64;
        #pragma unroll
        for (int it = 0; it < 16; it++) {
            int idx = it * 256 + t;
            int l = idx >> 6, c = idx & 63;
            tile[l][c] = Win[l * 256 + c0 + c];
        }
        __syncthreads();
        #pragma unroll
        for (int it = 0; it < 16; it++) {
            int idx = it * 256 + t;
            int c = idx >> 6, l = idx & 63;
            wT[(c0 + c) * 64 + l] = tile[l][c];
        }
    }
}

// ======= z = W_in @ x_tile + b_in (fp32 VALU, exact, reg-prefetch dbuf) =======
// Writes z (fp32) into the nearest-output region as scratch (own slice only).
__launch_bounds__(256, 4)
__global__ void zproj_kernel(const float* __restrict__ x,
                             const float* __restrict__ b_in,
                             const float* __restrict__ ws,
                             float* __restrict__ zg) {
    __shared__ __align__(16) float s_buf[2560];

    const int t  = threadIdx.x;
    const int b  = blockIdx.x >> 6;
    const int s0 = (blockIdx.x & 63) << 4;

    const int sgrp = t & 15;   // s (0..15)
    const int lgrp = t >> 4;   // l quad (0..15)
    float accz[4];             // [a=l]
    #pragma unroll
    for (int a = 0; a < 4; a++) accz[a] = b_in[lgrp * 4 + a];

    float2* s_x2 = (float2*)s_buf;            // x stage: [32 c][16 s], linear in t
    float4* s_w4 = (float4*)(s_buf + 512);    // w stage: [32 c][64 l], linear
    const float* s_xf = s_buf;
    const float* s_wf = s_buf + 512;
    const float2* x2  = (const float2*)x;
    const float4* wT4 = (const float4*)ws;

    const int xc = t >> 3, xs = t & 7;        // x tile: c row, s-pair
    const int wc = t >> 4, wq = t & 15;       // w tile: c row, l-quad

    float2 xr; float4 wr0, wr1;
    xr  = x2[(b * 256 + xc) * 512 + (s0 >> 1) + xs];
    wr0 = wT4[(wc)      * 16 + wq];
    wr1 = wT4[(wc + 16) * 16 + wq];

    for (int cc = 0; cc < 8; cc++) {
        __syncthreads();                 // previous compute done; LDS reusable
        s_x2[t]       = xr;
        s_w4[t]       = wr0;
        s_w4[256 + t] = wr1;
        __syncthreads();
        if (cc < 7) {                    // prefetch next tile; latency hides under FMAs
            xr  = x2[(b * 256 + (cc + 1) * 32 + xc) * 512 + (s0 >> 1) + xs];
            wr0 = wT4[((cc + 1) * 32 + wc)      * 16 + wq];
            wr1 = wT4[((cc + 1) * 32 + 16 + wc) * 16 + wq];
        }
        #pragma unroll 4
        for (int c = 0; c < 32; c++) {
            const float4 wv4 = *(const float4*)&s_wf[c * 64 + lgrp * 4];
            const float  xv  = s_xf[c * 16 + sgrp];
            const float wv[4] = {wv4.x, wv4.y, wv4.z, wv4.w};
            #pragma unroll
            for (int a = 0; a < 4; a++) accz[a] = fmaf(wv[a], xv, accz[a]);
        }
    }

    float4 zv;
    zv.x = accz[0]; zv.y = accz[1]; zv.z = accz[2]; zv.w = accz[3];
    *(float4*)&zg[(b * 1024 + s0 + sgrp) * 64 + lgrp * 4] = zv;
}

// ======= distances (bf16-split MFMA) + top-2 + recheck + gather + out-proj =======
__launch_bounds__(256, 4)
__global__ void vq_kernel(const float* __restrict__ cb,
                          const float* __restrict__ b_out,
                          const float* __restrict__ ws,
                          const float* zg,
                          float* out) {
    __shared__ __align__(16) float s_z[16 * 68];
    __shared__ __align__(16) float s_cbn[1024];
    __shared__ float s_rd1[64], s_rd2[64];
    __shared__ int   s_rk1[64], s_rk2[64];
    __shared__ int   s_ck[32];
    __shared__ float s_e[32];
    __shared__ int   s_ks[16];

    const int t  = threadIdx.x;
    const int b  = blockIdx.x >> 6;
    const int s0 = (blockIdx.x & 63) << 4;

    const unsigned short* cbh   = (const unsigned short*)(ws + 17408);
    const unsigned short* cbl   = cbh + 65536;
    const unsigned short* wouth = cbl + 65536;
    const unsigned short* woutl = wouth + 16384;

    // stage cbn -> LDS (256 f4)
    ((float4*)s_cbn)[t] = ((const float4*)(ws + 16384))[t];
    // stage z tile -> LDS (one coalesced f4 per thread; same bits as zproj wrote)
    {
        int s = t >> 4, q = t & 15;
        float4 zv = *(const float4*)&zg[(b * 1024 + s0 + s) * 64 + q * 4];
        *(float4*)&s_z[s * 68 + q * 4] = zv;
    }
    __syncthreads();

    const int w = t >> 6;                    // wave = code quarter (256 codes)
    const int lane = t & 63, quad = lane >> 4, n15 = lane & 15;

    // A-fragments: convert fp32 z -> bf16 hi/lo in registers (identical f2bf bits)
    short8v azh[2], azl[2];                  // [kh]
    #pragma unroll
    for (int kh = 0; kh < 2; kh++) {
        const float* zp = s_z + n15 * 68 + kh * 32 + quad * 8;
        float4 za = *(const float4*)zp;
        float4 zb = *(const float4*)(zp + 4);
        const float ze[8] = {za.x, za.y, za.z, za.w, zb.x, zb.y, zb.z, zb.w};
        short8v h8, l8;
        #pragma unroll
        for (int j = 0; j < 8; j++) {
            unsigned short h  = f2bf(ze[j]);
            unsigned short lo = f2bf(ze[j] - bf2f(h));
            h8[j] = (short)h; l8[j] = (short)lo;
        }
        azh[kh] = h8; azl[kh] = l8;
    }

    float d1[4], d2[4];
    int   k1[4], k2[4];
    #pragma unroll
    for (int r = 0; r < 4; r++) {
        d1[r] = FLT_MAX; d2[r] = FLT_MAX;
        k1[r] = 0;       k2[r] = 1;
    }

    for (int nt = 0; nt < 16; nt++) {
        const int krow = w * 256 + nt * 16 + n15;
        const unsigned short* bhp = cbh + krow * 64 + quad * 8;
        const unsigned short* blp = cbl + krow * 64 + quad * 8;
        short8v bh0 = *(const short8v*)(bhp);
        short8v bh1 = *(const short8v*)(bhp + 32);
        short8v bl0 = *(const short8v*)(blp);
        short8v bl1 = *(const short8v*)(blp + 32);
        float cn = s_cbn[krow];
        f32x4 acc = {0.f, 0.f, 0.f, 0.f};
        acc = MFMA16(azh[0], bh0, acc);
        acc = MFMA16(azh[1], bh1, acc);
        acc = MFMA16(azl[0], bh0, acc);
        acc = MFMA16(azl[1], bh1, acc);
        acc = MFMA16(azh[0], bl0, acc);
        acc = MFMA16(azh[1], bl1, acc);
        #pragma unroll
        for (int r = 0; r < 4; r++) {
            float d = fmaf(-2.f, acc[r], cn);
            bool lt1 = d < d1[r];
            bool lt2 = d < d2[r];
            d2[r] = lt1 ? d1[r] : (lt2 ? d : d2[r]);
            k2[r] = lt1 ? k1[r] : (lt2 ? krow : k2[r]);
            d1[r] = lt1 ? d : d1[r];
            k1[r] = lt1 ? krow : k1[r];
        }
    }

    // reduce top-2 across the 16 lanes of each quad (lexicographic, lower k on tie)
    #pragma unroll
    for (int r = 0; r < 4; r++) {
        float a1 = d1[r], a2 = d2[r];
        int   b1 = k1[r], b2 = k2[r];
        #pragma unroll
        for (int m = 1; m < 16; m <<= 1) {
            float c1 = __shfl_xor(a1, m), c2 = __shfl_xor(a2, m);
            int   e1 = __shfl_xor(b1, m), e2 = __shfl_xor(b2, m);
            bool aLEc = (a1 < c1) || (a1 == c1 && b1 <= e1);
            float nd1 = aLEc ? a1 : c1;  int nk1 = aLEc ? b1 : e1;
            float xd  = aLEc ? c1 : a1;  int xk  = aLEc ? e1 : b1;
            float yd  = aLEc ? a2 : c2;  int yk  = aLEc ? b2 : e2;
            bool xLEy = (xd < yd) || (xd == yd && xk <= yk);
            a1 = nd1; b1 = nk1;
            a2 = xLEy ? xd : yd;  b2 = xLEy ? xk : yk;
        }
        if (n15 == 0) {
            int pos = quad * 4 + r;
            s_rd1[pos * 4 + w] = a1; s_rk1[pos * 4 + w] = b1;
            s_rd2[pos * 4 + w] = a2; s_rk2[pos * 4 + w] = b2;
        }
    }
    __syncthreads();

    // merge the four code-quarters -> top-2 candidates per position (exact lex fold)
    if (t < 16) {
        float m1d = s_rd1[t * 4], m2d = s_rd2[t * 4];
        int   m1k = s_rk1[t * 4], m2k = s_rk2[t * 4];
        #pragma unroll
        for (int g = 1; g < 4; g++) {
            float c1 = s_rd1[t * 4 + g], c2 = s_rd2[t * 4 + g];
            int   e1 = s_rk1[t * 4 + g], e2 = s_rk2[t * 4 + g];
            bool aLEc = (m1d < c1) || (m1d == c1 && m1k <= e1);
            float nd1 = aLEc ? m1d : c1;  int nk1 = aLEc ? m1k : e1;
            float xd  = aLEc ? c1 : m1d;  int xk  = aLEc ? e1 : m1k;
            float yd  = aLEc ? m2d : c2;  int yk  = aLEc ? m2k : e2;
            bool xLEy = (xd < yd) || (xd == yd && xk <= yk);
            m1d = nd1; m1k = nk1;
            m2d = xLEy ? xd : yd;  m2k = xLEy ? xk : yk;
        }
        s_ck[t * 2]     = m1k;
        s_ck[t * 2 + 1] = m2k;
    }
    __syncthreads();

    // exact fp32 recheck of both candidates
    if (t < 32) {
        int pos = t >> 1;
        int k = s_ck[t];
        const float4* cbr = (const float4*)(cb + k * 64);
        float dot = 0.f;
        #pragma unroll
        for (int i = 0; i < 16; i++) {
            float4 zv = *(const float4*)&s_z[pos * 68 + i * 4];
            float4 cv = cbr[i];
            dot = fmaf(zv.x, cv.x, dot);
            dot = fmaf(zv.y, cv.y, dot);
            dot = fmaf(zv.z, cv.z, dot);
            dot = fmaf(zv.w, cv.w, dot);
        }
        s_e[t] = fmaf(-2.f, dot, s_cbn[k]);
    }
    __syncthreads();
    if (t < 16) {
        float e1 = s_e[t * 2], e2 = s_e[t * 2 + 1];
        int   c1 = s_ck[t * 2], c2 = s_ck[t * 2 + 1];
        bool take1 = (e1 < e2) || (e1 == e2 && c1 <= c2);
        s_ks[t] = take1 ? c1 : c2;
    }
    __syncthreads();

    // ======= gather nearest = cb[idx] (exact fp32; overwrites this block's z scratch) =======
    {
        float4* nearest4 = (float4*)(out + 8388608);
        const float4* cb4 = (const float4*)cb;
        int s = t >> 4, lq = t & 15;
        nearest4[(b * 1024 + s0 + s) * 16 + lq] = cb4[s_ks[s] * 16 + lq];
    }

    // ======= out = W_out @ nearest + b_out (bf16-split MFMA) =======
    {
        short8v ah[2], al[2];   // [kh]
        int k = s_ks[n15];
        #pragma unroll
        for (int kh = 0; kh < 2; kh++) {
            ah[kh] = *(const short8v*)(cbh + k * 64 + kh * 32 + quad * 8);
            al[kh] = *(const short8v*)(cbl + k * 64 + kh * 32 + quad * 8);
        }
        #pragma unroll
        for (int nt = 0; nt < 4; nt++) {
            int c = w * 64 + nt * 16 + n15;
            const unsigned short* bhp = wouth + c * 64 + quad * 8;
            const unsigned short* blp = woutl + c * 64 + quad * 8;
            short8v bh0 = *(const short8v*)(bhp);
            short8v bh1 = *(const short8v*)(bhp + 32);
            short8v bl0 = *(const short8v*)(blp);
            short8v bl1 = *(const short8v*)(blp + 32);
            float bo = b_out[c];
            f32x4 acc = {0.f, 0.f, 0.f, 0.f};
            acc = MFMA16(ah[0], bh0, acc);
            acc = MFMA16(ah[1], bh1, acc);
            acc = MFMA16(al[0], bh0, acc);
            acc = MFMA16(al[1], bh1, acc);
            acc = MFMA16(ah[0], bl0, acc);
            acc = MFMA16(ah[1], bl1, acc);
            float4 o;
            o.x = acc[0] + bo; o.y = acc[1] + bo; o.z = acc[2] + bo; o.w = acc[3] + bo;
            *(float4*)&out[(b * 256 + c) * 1024 + s0 + quad * 4] = o;
        }
    }
}

extern "C" void kernel_launch(void* const* d_in, const int* in_sizes, int n_in,
                              void* d_out, int out_size, void* d_ws, size_t ws_size,
                              hipStream_t stream) {
    const float* x    = (const float*)d_in[0];
    const float* cb   = (const float*)d_in[1];
    const float* Win  = (const float*)d_in[2];
    const float* bin  = (const float*)d_in[3];
    const float* Wout = (const float*)d_in[4];
    const float* bout = (const float*)d_in[5];
    float* out = (float*)d_out;
    float* ws  = (float*)d_ws;
    float* zg  = out + 8388608;   // nearest region doubles as z scratch

    prep_kernel<<<324, 256, 0, stream>>>(Win, Wout, cb, ws);
    zproj_kernel<<<2048, 256, 0, stream>>>(x, bin, ws, zg);
    vq_kernel<<<2048, 256, 0, stream>>>(cb, bout, ws, zg, out);
}

// Round 7
// 200.633 us; speedup vs baseline: 1.0786x; 1.0786x over previous
//
#include <hip/hip_runtime.h>
#include <float.h>

// B=32, C=256, HW=1024 (64 s-tiles of 16), K=1024, L=64
// d_out = [ out: 8388608 f32 ][ nearest: 2097152 f32 ]
//
// ws layout (float units):
//   wT   [256*64] @ 0      : wT[c*64+l] = W_in[l*256+c]           (fp32)
//   cbn  [1024]   @ 16384  : ||cb_k||^2                           (fp32)
//   cbh  [1024*64] ushort @ float-ofs 17408  (bf16 hi of cb)
//   cbl  [1024*64] ushort  (bf16 lo)
//   wouth[256*64]  ushort  (bf16 hi of W_out)
//   woutl[256*64]  ushort  (bf16 lo)
//
// Register-budget finding (r1-r6): on gfx950, kernels using MFMA get the
// per-wave VGPR budget SPLIT EVENLY between arch-VGPRs and AGPRs by the
// allocator. Measured: budget 64->arch 32 (r3), ~85->40 (r4), 128->64
// (r5/r6) -- spilling whenever phase-2 needs more arch regs than the half.
// Fix: vq_kernel uses __launch_bounds__(256,2) -> budget 256 -> arch cap 128,
// no spill; runtime occupancy follows actual usage (~5-6 waves/SIMD).
// zproj has no MFMA (no split) and keeps (256,4).

typedef __attribute__((ext_vector_type(8))) short short8v;
typedef __attribute__((ext_vector_type(4))) float f32x4;

#define MFMA16(A, B, C) __builtin_amdgcn_mfma_f32_16x16x32_bf16((A), (B), (C), 0, 0, 0)

__device__ __forceinline__ unsigned short f2bf(float f) {
    unsigned int u = __float_as_uint(f);
    u += 0x7FFFu + ((u >> 16) & 1u);
    return (unsigned short)(u >> 16);
}
__device__ __forceinline__ float bf2f(unsigned short h) {
    return __uint_as_float(((unsigned int)h) << 16);
}

__global__ void prep_kernel(const float* __restrict__ Win,
                            const float* __restrict__ Wout,
                            const float* __restrict__ cb,
                            float* __restrict__ ws) {
    __shared__ float tile[64][65];
    unsigned short* cbh   = (unsigned short*)(ws + 17408);
    unsigned short* cbl   = cbh + 65536;
    unsigned short* wouth = cbl + 65536;
    unsigned short* woutl = wouth + 16384;
    float* cbn = ws + 16384;
    float* wT  = ws;
    const int blk = blockIdx.x, t = threadIdx.x;

    if (blk < 256) {
        // codebook bf16 split + ||cb||^2 (one wave per code row: 64 lanes = 64 dims)
        int gid = blk * 256 + t;
        float v = cb[gid];
        unsigned short h = f2bf(v);
        cbh[gid] = h;
        cbl[gid] = f2bf(v - bf2f(h));
        float sq = v * v;
        #pragma unroll
        for (int m = 1; m < 64; m <<= 1) sq += __shfl_xor(sq, m);
        if ((t & 63) == 0) cbn[gid >> 6] = sq;
    } else if (blk < 320) {
        int gid = (blk - 256) * 256 + t;
        float v = Wout[gid];
        unsigned short h = f2bf(v);
        wouth[gid] = h;
        woutl[gid] = f2bf(v - bf2f(h));
    } else {
        // W_in transpose via LDS tile (coalesced both ways)
        int c0 = (blk - 320) * 64;
        #pragma unroll
        for (int it = 0; it < 16; it++) {
            int idx = it * 256 + t;
            int l = idx >> 6, c = idx & 63;
            tile[l][c] = Win[l * 256 + c0 + c];
        }
        __syncthreads();
        #pragma unroll
        for (int it = 0; it < 16; it++) {
            int idx = it * 256 + t;
            int c = idx >> 6, l = idx & 63;
            wT[(c0 + c) * 64 + l] = tile[l][c];
        }
    }
}

// ======= z = W_in @ x_tile + b_in (fp32 VALU, exact, reg-prefetch dbuf) =======
// Writes z (fp32) into the nearest-output region as scratch (own slice only).
__launch_bounds__(256, 4)
__global__ void zproj_kernel(const float* __restrict__ x,
                             const float* __restrict__ b_in,
                             const float* __restrict__ ws,
                             float* __restrict__ zg) {
    __shared__ __align__(16) float s_buf[2560];

    const int t  = threadIdx.x;
    const int b  = blockIdx.x >> 6;
    const int s0 = (blockIdx.x & 63) << 4;

    const int sgrp = t & 15;   // s (0..15)
    const int lgrp = t >> 4;   // l quad (0..15)
    float accz[4];             // [a=l]
    #pragma unroll
    for (int a = 0; a < 4; a++) accz[a] = b_in[lgrp * 4 + a];

    float2* s_x2 = (float2*)s_buf;            // x stage: [32 c][16 s], linear in t
    float4* s_w4 = (float4*)(s_buf + 512);    // w stage: [32 c][64 l], linear
    const float* s_xf = s_buf;
    const float* s_wf = s_buf + 512;
    const float2* x2  = (const float2*)x;
    const float4* wT4 = (const float4*)ws;

    const int xc = t >> 3, xs = t & 7;        // x tile: c row, s-pair
    const int wc = t >> 4, wq = t & 15;       // w tile: c row, l-quad

    float2 xr; float4 wr0, wr1;
    xr  = x2[(b * 256 + xc) * 512 + (s0 >> 1) + xs];
    wr0 = wT4[(wc)      * 16 + wq];
    wr1 = wT4[(wc + 16) * 16 + wq];

    for (int cc = 0; cc < 8; cc++) {
        __syncthreads();                 // previous compute done; LDS reusable
        s_x2[t]       = xr;
        s_w4[t]       = wr0;
        s_w4[256 + t] = wr1;
        __syncthreads();
        if (cc < 7) {                    // prefetch next tile; latency hides under FMAs
            xr  = x2[(b * 256 + (cc + 1) * 32 + xc) * 512 + (s0 >> 1) + xs];
            wr0 = wT4[((cc + 1) * 32 + wc)      * 16 + wq];
            wr1 = wT4[((cc + 1) * 32 + 16 + wc) * 16 + wq];
        }
        #pragma unroll 4
        for (int c = 0; c < 32; c++) {
            const float4 wv4 = *(const float4*)&s_wf[c * 64 + lgrp * 4];
            const float  xv  = s_xf[c * 16 + sgrp];
            const float wv[4] = {wv4.x, wv4.y, wv4.z, wv4.w};
            #pragma unroll
            for (int a = 0; a < 4; a++) accz[a] = fmaf(wv[a], xv, accz[a]);
        }
    }

    float4 zv;
    zv.x = accz[0]; zv.y = accz[1]; zv.z = accz[2]; zv.w = accz[3];
    *(float4*)&zg[(b * 1024 + s0 + sgrp) * 64 + lgrp * 4] = zv;
}

// ======= distances (bf16-split MFMA) + top-2 + recheck + gather + out-proj =======
__launch_bounds__(256, 2)
__global__ void vq_kernel(const float* __restrict__ cb,
                          const float* __restrict__ b_out,
                          const float* __restrict__ ws,
                          const float* zg,
                          float* out) {
    __shared__ __align__(16) float s_z[16 * 68];
    __shared__ __align__(16) float s_cbn[1024];
    __shared__ float s_rd1[64], s_rd2[64];
    __shared__ int   s_rk1[64], s_rk2[64];
    __shared__ int   s_ck[32];
    __shared__ float s_e[32];
    __shared__ int   s_ks[16];

    const int t  = threadIdx.x;
    const int b  = blockIdx.x >> 6;
    const int s0 = (blockIdx.x & 63) << 4;

    const unsigned short* cbh   = (const unsigned short*)(ws + 17408);
    const unsigned short* cbl   = cbh + 65536;
    const unsigned short* wouth = cbl + 65536;
    const unsigned short* woutl = wouth + 16384;

    // stage cbn -> LDS (256 f4)
    ((float4*)s_cbn)[t] = ((const float4*)(ws + 16384))[t];
    // stage z tile -> LDS (one coalesced f4 per thread; same bits as zproj wrote)
    {
        int s = t >> 4, q = t & 15;
        float4 zv = *(const float4*)&zg[(b * 1024 + s0 + s) * 64 + q * 4];
        *(float4*)&s_z[s * 68 + q * 4] = zv;
    }
    __syncthreads();

    const int w = t >> 6;                    // wave = code quarter (256 codes)
    const int lane = t & 63, quad = lane >> 4, n15 = lane & 15;

    // A-fragments: convert fp32 z -> bf16 hi/lo in registers (identical f2bf bits)
    short8v azh[2], azl[2];                  // [kh]
    #pragma unroll
    for (int kh = 0; kh < 2; kh++) {
        const float* zp = s_z + n15 * 68 + kh * 32 + quad * 8;
        float4 za = *(const float4*)zp;
        float4 zb = *(const float4*)(zp + 4);
        const float ze[8] = {za.x, za.y, za.z, za.w, zb.x, zb.y, zb.z, zb.w};
        short8v h8, l8;
        #pragma unroll
        for (int j = 0; j < 8; j++) {
            unsigned short h  = f2bf(ze[j]);
            unsigned short lo = f2bf(ze[j] - bf2f(h));
            h8[j] = (short)h; l8[j] = (short)lo;
        }
        azh[kh] = h8; azl[kh] = l8;
    }

    float d1[4], d2[4];
    int   k1[4], k2[4];
    #pragma unroll
    for (int r = 0; r < 4; r++) {
        d1[r] = FLT_MAX; d2[r] = FLT_MAX;
        k1[r] = 0;       k2[r] = 1;
    }

    for (int nt = 0; nt < 16; nt++) {
        const int krow = w * 256 + nt * 16 + n15;
        const unsigned short* bhp = cbh + krow * 64 + quad * 8;
        const unsigned short* blp = cbl + krow * 64 + quad * 8;
        short8v bh0 = *(const short8v*)(bhp);
        short8v bh1 = *(const short8v*)(bhp + 32);
        short8v bl0 = *(const short8v*)(blp);
        short8v bl1 = *(const short8v*)(blp + 32);
        float cn = s_cbn[krow];
        f32x4 acc = {0.f, 0.f, 0.f, 0.f};
        acc = MFMA16(azh[0], bh0, acc);
        acc = MFMA16(azh[1], bh1, acc);
        acc = MFMA16(azl[0], bh0, acc);
        acc = MFMA16(azl[1], bh1, acc);
        acc = MFMA16(azh[0], bl0, acc);
        acc = MFMA16(azh[1], bl1, acc);
        #pragma unroll
        for (int r = 0; r < 4; r++) {
            float d = fmaf(-2.f, acc[r], cn);
            bool lt1 = d < d1[r];
            bool lt2 = d < d2[r];
            d2[r] = lt1 ? d1[r] : (lt2 ? d : d2[r]);
            k2[r] = lt1 ? k1[r] : (lt2 ? krow : k2[r]);
            d1[r] = lt1 ? d : d1[r];
            k1[r] = lt1 ? krow : k1[r];
        }
    }

    // reduce top-2 across the 16 lanes of each quad (lexicographic, lower k on tie)
    #pragma unroll
    for (int r = 0; r < 4; r++) {
        float a1 = d1[r], a2 = d2[r];
        int   b1 = k1[r], b2 = k2[r];
        #pragma unroll
        for (int m = 1; m < 16; m <<= 1) {
            float c1 = __shfl_xor(a1, m), c2 = __shfl_xor(a2, m);
            int   e1 = __shfl_xor(b1, m), e2 = __shfl_xor(b2, m);
            bool aLEc = (a1 < c1) || (a1 == c1 && b1 <= e1);
            float nd1 = aLEc ? a1 : c1;  int nk1 = aLEc ? b1 : e1;
            float xd  = aLEc ? c1 : a1;  int xk  = aLEc ? e1 : b1;
            float yd  = aLEc ? a2 : c2;  int yk  = aLEc ? b2 : e2;
            bool xLEy = (xd < yd) || (xd == yd && xk <= yk);
            a1 = nd1; b1 = nk1;
            a2 = xLEy ? xd : yd;  b2 = xLEy ? xk : yk;
        }
        if (n15 == 0) {
            int pos = quad * 4 + r;
            s_rd1[pos * 4 + w] = a1; s_rk1[pos * 4 + w] = b1;
            s_rd2[pos * 4 + w] = a2; s_rk2[pos * 4 + w] = b2;
        }
    }
    __syncthreads();

    // merge the four code-quarters -> top-2 candidates per position (exact lex fold)
    if (t < 16) {
        float m1d = s_rd1[t * 4], m2d = s_rd2[t * 4];
        int   m1k = s_rk1[t * 4], m2k = s_rk2[t * 4];
        #pragma unroll
        for (int g = 1; g < 4; g++) {
            float c1 = s_rd1[t * 4 + g], c2 = s_rd2[t * 4 + g];
            int   e1 = s_rk1[t * 4 + g], e2 = s_rk2[t * 4 + g];
            bool aLEc = (m1d < c1) || (m1d == c1 && m1k <= e1);
            float nd1 = aLEc ? m1d : c1;  int nk1 = aLEc ? m1k : e1;
            float xd  = aLEc ? c1 : m1d;  int xk  = aLEc ? e1 : m1k;
            float yd  = aLEc ? m2d : c2;  int yk  = aLEc ? m2k : e2;
            bool xLEy = (xd < yd) || (xd == yd && xk <= yk);
            m1d = nd1; m1k = nk1;
            m2d = xLEy ? xd : yd;  m2k = xLEy ? xk : yk;
        }
        s_ck[t * 2]     = m1k;
        s_ck[t * 2 + 1] = m2k;
    }
    __syncthreads();

    // exact fp32 recheck of both candidates
    if (t < 32) {
        int pos = t >> 1;
        int k = s_ck[t];
        const float4* cbr = (const float4*)(cb + k * 64);
        float dot = 0.f;
        #pragma unroll
        for (int i = 0; i < 16; i++) {
            float4 zv = *(const float4*)&s_z[pos * 68 + i * 4];
            float4 cv = cbr[i];
            dot = fmaf(zv.x, cv.x, dot);
            dot = fmaf(zv.y, cv.y, dot);
            dot = fmaf(zv.z, cv.z, dot);
            dot = fmaf(zv.w, cv.w, dot);
        }
        s_e[t] = fmaf(-2.f, dot, s_cbn[k]);
    }
    __syncthreads();
    if (t < 16) {
        float e1 = s_e[t * 2], e2 = s_e[t * 2 + 1];
        int   c1 = s_ck[t * 2], c2 = s_ck[t * 2 + 1];
        bool take1 = (e1 < e2) || (e1 == e2 && c1 <= c2);
        s_ks[t] = take1 ? c1 : c2;
    }
    __syncthreads();

    // ======= gather nearest = cb[idx] (exact fp32; overwrites this block's z scratch) =======
    {
        float4* nearest4 = (float4*)(out + 8388608);
        const float4* cb4 = (const float4*)cb;
        int s = t >> 4, lq = t & 15;
        nearest4[(b * 1024 + s0 + s) * 16 + lq] = cb4[s_ks[s] * 16 + lq];
    }

    // ======= out = W_out @ nearest + b_out (bf16-split MFMA) =======
    {
        short8v ah[2], al[2];   // [kh]
        int k = s_ks[n15];
        #pragma unroll
        for (int kh = 0; kh < 2; kh++) {
            ah[kh] = *(const short8v*)(cbh + k * 64 + kh * 32 + quad * 8);
            al[kh] = *(const short8v*)(cbl + k * 64 + kh * 32 + quad * 8);
        }
        #pragma unroll
        for (int nt = 0; nt < 4; nt++) {
            int c = w * 64 + nt * 16 + n15;
            const unsigned short* bhp = wouth + c * 64 + quad * 8;
            const unsigned short* blp = woutl + c * 64 + quad * 8;
            short8v bh0 = *(const short8v*)(bhp);
            short8v bh1 = *(const short8v*)(bhp + 32);
            short8v bl0 = *(const short8v*)(blp);
            short8v bl1 = *(const short8v*)(blp + 32);
            float bo = b_out[c];
            f32x4 acc = {0.f, 0.f, 0.f, 0.f};
            acc = MFMA16(ah[0], bh0, acc);
            acc = MFMA16(ah[1], bh1, acc);
            acc = MFMA16(al[0], bh0, acc);
            acc = MFMA16(al[1], bh1, acc);
            acc = MFMA16(ah[0], bl0, acc);
            acc = MFMA16(ah[1], bl1, acc);
            float4 o;
            o.x = acc[0] + bo; o.y = acc[1] + bo; o.z = acc[2] + bo; o.w = acc[3] + bo;
            *(float4*)&out[(b * 256 + c) * 1024 + s0 + quad * 4] = o;
        }
    }
}

extern "C" void kernel_launch(void* const* d_in, const int* in_sizes, int n_in,
                              void* d_out, int out_size, void* d_ws, size_t ws_size,
                              hipStream_t stream) {
    const float* x    = (const float*)d_in[0];
    const float* cb   = (const float*)d_in[1];
    const float* Win  = (const float*)d_in[2];
    const float* bin  = (const float*)d_in[3];
    const float* Wout = (const float*)d_in[4];
    const float* bout = (const float*)d_in[5];
    float* out = (float*)d_out;
    float* ws  = (float*)d_ws;
    float* zg  = out + 8388608;   // nearest region doubles as z scratch

    prep_kernel<<<324, 256, 0, stream>>>(Win, Wout, cb, ws);
    zproj_kernel<<<2048, 256, 0, stream>>>(x, bin, ws, zg);
    vq_kernel<<<2048, 256, 0, stream>>>(cb, bout, ws, zg, out);
}

// Round 9
// 146.697 us; speedup vs baseline: 1.4752x; 1.3677x over previous
//
#include <hip/hip_runtime.h>
#include <float.h>

// B=32, C=256, HW=1024 (32 s-tiles of 32), K=1024, L=64
// d_out = [ out: 8388608 f32 ][ nearest: 2097152 f32 ]
//
// ws layout (float units):
//   wT   [256*64] @ 0      : wT[c*64+l] = W_in[l*256+c]           (fp32)
//   cbn  [1024]   @ 16384  : ||cb_k||^2                           (fp32)
//   cbh  [1024*64] ushort @ float-ofs 17408  (bf16 hi of cb)
//   cbl  [1024*64] ushort  (bf16 lo)
//   wouth[256*64]  ushort  (bf16 hi of W_out)
//   woutl[256*64]  ushort  (bf16 lo)
//
// Base: the verified 73us round-1 kernel (grid 1024, 32-pos tiles, 4 code
// quarters). Exactly two changes this round:
//  (a) __launch_bounds__ (256,4) -> (256,2): MFMA kernels get only ~half the
//      budget as arch VGPRs (r3-r7 series); prefetch needs ~73 arch regs.
//  (b) phase-2 nt-loop register double-buffer: prefetch B-tiles + cbn for
//      nt+1 while computing nt (hides ~200-400cy L2 latency x 16 iters).

typedef __attribute__((ext_vector_type(8))) short short8v;
typedef __attribute__((ext_vector_type(4))) float f32x4;

#define MFMA16(A, B, C) __builtin_amdgcn_mfma_f32_16x16x32_bf16((A), (B), (C), 0, 0, 0)

__device__ __forceinline__ unsigned short f2bf(float f) {
    unsigned int u = __float_as_uint(f);
    u += 0x7FFFu + ((u >> 16) & 1u);
    return (unsigned short)(u >> 16);
}
__device__ __forceinline__ float bf2f(unsigned short h) {
    return __uint_as_float(((unsigned int)h) << 16);
}

__global__ void prep_kernel(const float* __restrict__ Win,
                            const float* __restrict__ Wout,
                            const float* __restrict__ cb,
                            float* __restrict__ ws) {
    __shared__ float tile[64][65];
    unsigned short* cbh   = (unsigned short*)(ws + 17408);
    unsigned short* cbl   = cbh + 65536;
    unsigned short* wouth = cbl + 65536;
    unsigned short* woutl = wouth + 16384;
    float* cbn = ws + 16384;
    float* wT  = ws;
    const int blk = blockIdx.x, t = threadIdx.x;

    if (blk < 256) {
        // codebook bf16 split + ||cb||^2 (one wave per code row: 64 lanes = 64 dims)
        int gid = blk * 256 + t;
        float v = cb[gid];
        unsigned short h = f2bf(v);
        cbh[gid] = h;
        cbl[gid] = f2bf(v - bf2f(h));
        float sq = v * v;
        #pragma unroll
        for (int m = 1; m < 64; m <<= 1) sq += __shfl_xor(sq, m);
        if ((t & 63) == 0) cbn[gid >> 6] = sq;
    } else if (blk < 320) {
        int gid = (blk - 256) * 256 + t;
        float v = Wout[gid];
        unsigned short h = f2bf(v);
        wouth[gid] = h;
        woutl[gid] = f2bf(v - bf2f(h));
    } else {
        // W_in transpose via LDS tile (coalesced both ways)
        int c0 = (blk - 320) * 64;
        #pragma unroll
        for (int it = 0; it < 16; it++) {
            int idx = it * 256 + t;
            int l = idx >> 6, c = idx & 63;
            tile[l][c] = Win[l * 256 + c0 + c];
        }
        __syncthreads();
        #pragma unroll
        for (int it = 0; it < 16; it++) {
            int idx = it * 256 + t;
            int c = idx >> 6, l = idx & 63;
            wT[(c0 + c) * 64 + l] = tile[l][c];
        }
    }
}

__launch_bounds__(256, 2)
__global__ void vq_kernel(const float* __restrict__ x,
                          const float* __restrict__ cb,
                          const float* __restrict__ b_in,
                          const float* __restrict__ b_out,
                          const float* __restrict__ ws,
                          float* __restrict__ out) {
    // union buffer: phase1 staging (x: 1024 f, w: 2048 f) then s_z [32][68] fp32
    __shared__ __align__(16) float s_buf[3072];
    __shared__ __align__(16) float s_cbn[1024];
    __shared__ float s_rd1[128], s_rd2[128];
    __shared__ int   s_rk1[128], s_rk2[128];
    __shared__ int   s_ck[64];
    __shared__ float s_e[64];
    __shared__ int   s_ks[32];

    const int t  = threadIdx.x;
    const int b  = blockIdx.x >> 5;
    const int s0 = (blockIdx.x & 31) << 5;

    const unsigned short* cbh   = (const unsigned short*)(ws + 17408);
    const unsigned short* cbl   = cbh + 65536;
    const unsigned short* wouth = cbl + 65536;
    const unsigned short* woutl = wouth + 16384;

    // stage cbn -> LDS (256 f4)
    ((float4*)s_cbn)[t] = ((const float4*)(ws + 16384))[t];

    // ======= phase 1: z = W_in @ x_tile + b_in (fp32 VALU, exact, reg-prefetch dbuf) =======
    const int sgrp = t & 15;   // s pair (2 s each)
    const int lgrp = t >> 4;   // l quad (0..15)
    float accz[4][2];          // [a=l][i=s]
    #pragma unroll
    for (int a = 0; a < 4; a++) {
        float bi = b_in[lgrp * 4 + a];
        #pragma unroll
        for (int i = 0; i < 2; i++) accz[a][i] = bi;
    }

    float4* s_x4 = (float4*)s_buf;            // x stage: [c][sq] f4, linear in t
    float4* s_w4 = (float4*)(s_buf + 1024);   // w stage: [c][l] f4, linear
    const float* s_xf = s_buf;
    const float* s_wf = s_buf + 1024;
    const float4* x4  = (const float4*)x;
    const float4* wT4 = (const float4*)ws;

    const int xc = t >> 3, xq = t & 7;        // x tile: c row, s-quad
    const int wc = t >> 4, wq = t & 15;       // w tile: c row, l-quad

    float4 xr, wr0, wr1;
    xr  = x4[(b * 256 + xc) * 256 + (s0 >> 2) + xq];
    wr0 = wT4[(wc)      * 16 + wq];
    wr1 = wT4[(wc + 16) * 16 + wq];

    for (int cc = 0; cc < 8; cc++) {
        __syncthreads();                 // previous compute done; LDS reusable
        s_x4[t]       = xr;
        s_w4[t]       = wr0;
        s_w4[256 + t] = wr1;
        __syncthreads();
        if (cc < 7) {                    // prefetch next tile; latency hides under FMAs
            xr  = x4[(b * 256 + (cc + 1) * 32 + xc) * 256 + (s0 >> 2) + xq];
            wr0 = wT4[((cc + 1) * 32 + wc)      * 16 + wq];
            wr1 = wT4[((cc + 1) * 32 + 16 + wc) * 16 + wq];
        }
        #pragma unroll 4
        for (int c = 0; c < 32; c++) {
            const float4 wv4 = *(const float4*)&s_wf[c * 64 + lgrp * 4];
            const float2 xv2 = *(const float2*)&s_xf[c * 32 + sgrp * 2];
            const float wv[4] = {wv4.x, wv4.y, wv4.z, wv4.w};
            const float xv[2] = {xv2.x, xv2.y};
            #pragma unroll
            for (int a = 0; a < 4; a++)
                #pragma unroll
                for (int i = 0; i < 2; i++)
                    accz[a][i] = fmaf(wv[a], xv[i], accz[a][i]);
        }
    }
    __syncthreads();  // staging dead; reuse s_buf as s_z

    float* s_z = s_buf;                  // [32][68] fp32
    #pragma unroll
    for (int i = 0; i < 2; i++) {
        int s = sgrp * 2 + i;
        float4 zv;
        zv.x = accz[0][i]; zv.y = accz[1][i]; zv.z = accz[2][i]; zv.w = accz[3][i];
        *(float4*)&s_z[s * 68 + lgrp * 4] = zv;
    }
    __syncthreads();

    // ======= phase 2: approx distances via bf16-split MFMA + top-2 (4 code quarters) =======
    const int w = t >> 6;                    // wave = code quarter (256 codes)
    const int lane = t & 63, quad = lane >> 4, n15 = lane & 15;

    // A-fragments: convert fp32 z -> bf16 hi/lo in registers (identical f2bf bits)
    short8v azh[2][2], azl[2][2];            // [mt][kh]
    #pragma unroll
    for (int mt = 0; mt < 2; mt++)
        #pragma unroll
        for (int kh = 0; kh < 2; kh++) {
            const float* zp = s_z + (mt * 16 + n15) * 68 + kh * 32 + quad * 8;
            float4 za = *(const float4*)zp;
            float4 zb = *(const float4*)(zp + 4);
            const float ze[8] = {za.x, za.y, za.z, za.w, zb.x, zb.y, zb.z, zb.w};
            short8v h8, l8;
            #pragma unroll
            for (int j = 0; j < 8; j++) {
                unsigned short h  = f2bf(ze[j]);
                unsigned short lo = f2bf(ze[j] - bf2f(h));
                h8[j] = (short)h; l8[j] = (short)lo;
            }
            azh[mt][kh] = h8; azl[mt][kh] = l8;
        }

    float d1[2][4], d2[2][4];
    int   k1[2][4], k2[2][4];
    #pragma unroll
    for (int mt = 0; mt < 2; mt++)
        #pragma unroll
        for (int r = 0; r < 4; r++) {
            d1[mt][r] = FLT_MAX; d2[mt][r] = FLT_MAX;
            k1[mt][r] = 0;       k2[mt][r] = 1;
        }

    // nt-loop with register double-buffered B-tile prefetch (this round's change)
    {
        const int kbase = w * 256 + n15;
        const unsigned short* pbh = cbh + kbase * 64 + quad * 8;
        const unsigned short* pbl = cbl + kbase * 64 + quad * 8;
        short8v ubh0 = *(const short8v*)(pbh);
        short8v ubh1 = *(const short8v*)(pbh + 32);
        short8v ubl0 = *(const short8v*)(pbl);
        short8v ubl1 = *(const short8v*)(pbl + 32);
        float   ucn  = s_cbn[kbase];

        for (int nt = 0; nt < 16; nt++) {
            const int krow = w * 256 + nt * 16 + n15;
            const short8v bh0 = ubh0, bh1 = ubh1, bl0 = ubl0, bl1 = ubl1;
            const float cn = ucn;
            if (nt < 15) {               // prefetch next 16-code tile (krow+16)
                const unsigned short* nbh = cbh + (krow + 16) * 64 + quad * 8;
                const unsigned short* nbl = cbl + (krow + 16) * 64 + quad * 8;
                ubh0 = *(const short8v*)(nbh);
                ubh1 = *(const short8v*)(nbh + 32);
                ubl0 = *(const short8v*)(nbl);
                ubl1 = *(const short8v*)(nbl + 32);
                ucn  = s_cbn[krow + 16];
            }
            #pragma unroll
            for (int mt = 0; mt < 2; mt++) {
                f32x4 acc = {0.f, 0.f, 0.f, 0.f};
                acc = MFMA16(azh[mt][0], bh0, acc);
                acc = MFMA16(azh[mt][1], bh1, acc);
                acc = MFMA16(azl[mt][0], bh0, acc);
                acc = MFMA16(azl[mt][1], bh1, acc);
                acc = MFMA16(azh[mt][0], bl0, acc);
                acc = MFMA16(azh[mt][1], bl1, acc);
                #pragma unroll
                for (int r = 0; r < 4; r++) {
                    float d = fmaf(-2.f, acc[r], cn);
                    bool lt1 = d < d1[mt][r];
                    bool lt2 = d < d2[mt][r];
                    d2[mt][r] = lt1 ? d1[mt][r] : (lt2 ? d : d2[mt][r]);
                    k2[mt][r] = lt1 ? k1[mt][r] : (lt2 ? krow : k2[mt][r]);
                    d1[mt][r] = lt1 ? d : d1[mt][r];
                    k1[mt][r] = lt1 ? krow : k1[mt][r];
                }
            }
        }
    }

    // reduce top-2 across the 16 lanes of each quad (lexicographic, lower k on tie)
    #pragma unroll
    for (int mt = 0; mt < 2; mt++)
        #pragma unroll
        for (int r = 0; r < 4; r++) {
            float a1 = d1[mt][r], a2 = d2[mt][r];
            int   b1 = k1[mt][r], b2 = k2[mt][r];
            #pragma unroll
            for (int m = 1; m < 16; m <<= 1) {
                float c1 = __shfl_xor(a1, m), c2 = __shfl_xor(a2, m);
                int   e1 = __shfl_xor(b1, m), e2 = __shfl_xor(b2, m);
                bool aLEc = (a1 < c1) || (a1 == c1 && b1 <= e1);
                float nd1 = aLEc ? a1 : c1;  int nk1 = aLEc ? b1 : e1;
                float xd  = aLEc ? c1 : a1;  int xk  = aLEc ? e1 : b1;
                float yd  = aLEc ? a2 : c2;  int yk  = aLEc ? b2 : e2;
                bool xLEy = (xd < yd) || (xd == yd && xk <= yk);
                a1 = nd1; b1 = nk1;
                a2 = xLEy ? xd : yd;  b2 = xLEy ? xk : yk;
            }
            if (n15 == 0) {
                int pos = mt * 16 + quad * 4 + r;
                s_rd1[pos * 4 + w] = a1; s_rk1[pos * 4 + w] = b1;
                s_rd2[pos * 4 + w] = a2; s_rk2[pos * 4 + w] = b2;
            }
        }
    __syncthreads();

    // merge the four code-quarters -> top-2 candidates per position (exact lex fold)
    if (t < 32) {
        float m1d = s_rd1[t * 4], m2d = s_rd2[t * 4];
        int   m1k = s_rk1[t * 4], m2k = s_rk2[t * 4];
        #pragma unroll
        for (int g = 1; g < 4; g++) {
            float c1 = s_rd1[t * 4 + g], c2 = s_rd2[t * 4 + g];
            int   e1 = s_rk1[t * 4 + g], e2 = s_rk2[t * 4 + g];
            bool aLEc = (m1d < c1) || (m1d == c1 && m1k <= e1);
            float nd1 = aLEc ? m1d : c1;  int nk1 = aLEc ? m1k : e1;
            float xd  = aLEc ? c1 : m1d;  int xk  = aLEc ? e1 : m1k;
            float yd  = aLEc ? m2d : c2;  int yk  = aLEc ? m2k : e2;
            bool xLEy = (xd < yd) || (xd == yd && xk <= yk);
            m1d = nd1; m1k = nk1;
            m2d = xLEy ? xd : yd;  m2k = xLEy ? xk : yk;
        }
        s_ck[t * 2]     = m1k;
        s_ck[t * 2 + 1] = m2k;
    }
    __syncthreads();

    // exact fp32 recheck of both candidates
    if (t < 64) {
        int pos = t >> 1;
        int k = s_ck[t];
        const float4* cbr = (const float4*)(cb + k * 64);
        float dot = 0.f;
        #pragma unroll
        for (int i = 0; i < 16; i++) {
            float4 zv = *(const float4*)&s_z[pos * 68 + i * 4];
            float4 cv = cbr[i];
            dot = fmaf(zv.x, cv.x, dot);
            dot = fmaf(zv.y, cv.y, dot);
            dot = fmaf(zv.z, cv.z, dot);
            dot = fmaf(zv.w, cv.w, dot);
        }
        s_e[t] = fmaf(-2.f, dot, s_cbn[k]);
    }
    __syncthreads();
    if (t < 32) {
        float e1 = s_e[t * 2], e2 = s_e[t * 2 + 1];
        int   c1 = s_ck[t * 2], c2 = s_ck[t * 2 + 1];
        bool take1 = (e1 < e2) || (e1 == e2 && c1 <= c2);
        s_ks[t] = take1 ? c1 : c2;
    }
    __syncthreads();

    // ======= gather nearest = cb[idx] (exact fp32) =======
    {
        float4* nearest4 = (float4*)(out + 8388608);
        const float4* cb4 = (const float4*)cb;
        #pragma unroll
        for (int it = 0; it < 2; it++) {
            int idx = it * 256 + t;
            int s = idx >> 4, lq = idx & 15;
            nearest4[(b * 1024 + s0 + s) * 16 + lq] = cb4[s_ks[s] * 16 + lq];
        }
    }

    // ======= phase 3: out = W_out @ nearest + b_out (bf16-split MFMA) =======
    {
        short8v ah[2][2], al[2][2];   // [mt][kh]
        #pragma unroll
        for (int mt = 0; mt < 2; mt++) {
            int k = s_ks[mt * 16 + n15];
            #pragma unroll
            for (int kh = 0; kh < 2; kh++) {
                ah[mt][kh] = *(const short8v*)(cbh + k * 64 + kh * 32 + quad * 8);
                al[mt][kh] = *(const short8v*)(cbl + k * 64 + kh * 32 + quad * 8);
            }
        }
        #pragma unroll
        for (int nt = 0; nt < 4; nt++) {
            int c = w * 64 + nt * 16 + n15;
            const unsigned short* bhp = wouth + c * 64 + quad * 8;
            const unsigned short* blp = woutl + c * 64 + quad * 8;
            short8v bh0 = *(const short8v*)(bhp);
            short8v bh1 = *(const short8v*)(bhp + 32);
            short8v bl0 = *(const short8v*)(blp);
            short8v bl1 = *(const short8v*)(blp + 32);
            float bo = b_out[c];
            #pragma unroll
            for (int mt = 0; mt < 2; mt++) {
                f32x4 acc = {0.f, 0.f, 0.f, 0.f};
                acc = MFMA16(ah[mt][0], bh0, acc);
                acc = MFMA16(ah[mt][1], bh1, acc);
                acc = MFMA16(al[mt][0], bh0, acc);
                acc = MFMA16(al[mt][1], bh1, acc);
                acc = MFMA16(ah[mt][0], bl0, acc);
                acc = MFMA16(ah[mt][1], bl1, acc);
                float4 o;
                o.x = acc[0] + bo; o.y = acc[1] + bo; o.z = acc[2] + bo; o.w = acc[3] + bo;
                *(float4*)&out[(b * 256 + c) * 1024 + s0 + mt * 16 + quad * 4] = o;
            }
        }
    }
}

extern "C" void kernel_launch(void* const* d_in, const int* in_sizes, int n_in,
                              void* d_out, int out_size, void* d_ws, size_t ws_size,
                              hipStream_t stream) {
    const float* x    = (const float*)d_in[0];
    const float* cb   = (const float*)d_in[1];
    const float* Win  = (const float*)d_in[2];
    const float* bin  = (const float*)d_in[3];
    const float* Wout = (const float*)d_in[4];
    const float* bout = (const float*)d_in[5];
    float* out = (float*)d_out;
    float* ws  = (float*)d_ws;

    prep_kernel<<<324, 256, 0, stream>>>(Win, Wout, cb, ws);
    vq_kernel<<<1024, 256, 0, stream>>>(x, cb, bin, bout, ws, out);
}